// Round 3
// baseline (591.527 us; speedup 1.0000x reference)
//
#include <hip/hip_runtime.h>
#include <cstdint>

// ---- problem constants ----
#define B_SZ   64
#define SEQ    197
#define DIM    768
#define NHEAD  12
#define HDK    64
#define MLP_D  3072
#define RH_D   512
#define RANK_D 256
#define NEXP   3
#define TOK    (B_SZ*SEQ)   // 12608

typedef unsigned short u16;
typedef __attribute__((ext_vector_type(8))) short s16x8;
typedef __attribute__((ext_vector_type(4))) float f32x4;

static __device__ __forceinline__ u16 f2bf(float f) {
  unsigned u = __builtin_bit_cast(unsigned, f);
  u = u + 0x7FFFu + ((u >> 16) & 1u);
  return (u16)(u >> 16);
}

static __device__ __forceinline__ f32x4 mfma16(s16x8 a, s16x8 b, f32x4 c) {
  return __builtin_amdgcn_mfma_f32_16x16x32_bf16(a, b, c, 0, 0, 0);
}

// ---- f32 -> bf16 convert (vector x4) ----
__global__ void cvt_bf16(const float* __restrict__ in, u16* __restrict__ out, long n) {
  long i = ((long)blockIdx.x * blockDim.x + threadIdx.x) * 4;
  const long stride = (long)gridDim.x * blockDim.x * 4;
  for (; i < n; i += stride) {
    float4 v = *(const float4*)(in + i);
    unsigned r0 = (unsigned)f2bf(v.x) | ((unsigned)f2bf(v.y) << 16);
    unsigned r1 = (unsigned)f2bf(v.z) | ((unsigned)f2bf(v.w) << 16);
    *(uint2*)(out + i) = make_uint2(r0, r1);
  }
}

__global__ void concat3(const float* __restrict__ a, const float* __restrict__ b,
                        const float* __restrict__ c, float* __restrict__ out) {
  int i = blockIdx.x * 256 + threadIdx.x;
  if (i < DIM) { out[i] = a[i]; out[DIM + i] = b[i]; out[2*DIM + i] = c[i]; }
}

// ---- LayerNorm over D=768, f32 in -> bf16 out. 4 rows/block (wave per row) ----
__global__ __launch_bounds__(256) void ln_rows(
    const float* __restrict__ x, const float* __restrict__ g,
    const float* __restrict__ bb, u16* __restrict__ out, int M)
{
  const int row = blockIdx.x * 4 + (threadIdx.x >> 6);
  const int lane = threadIdx.x & 63;
  if (row >= M) return;
  const float* xr = x + (long)row * DIM;
  float4 v[3];
  float s = 0.f, s2 = 0.f;
#pragma unroll
  for (int c = 0; c < 3; ++c) {
    v[c] = *(const float4*)(xr + c*256 + lane*4);
    s  += v[c].x + v[c].y + v[c].z + v[c].w;
    s2 += v[c].x*v[c].x + v[c].y*v[c].y + v[c].z*v[c].z + v[c].w*v[c].w;
  }
#pragma unroll
  for (int o = 1; o < 64; o <<= 1) { s += __shfl_xor(s, o); s2 += __shfl_xor(s2, o); }
  const float mean = s * (1.f/DIM);
  const float var  = s2 * (1.f/DIM) - mean*mean;
  const float rstd = rsqrtf(fmaxf(var, 0.f) + 1e-5f);
#pragma unroll
  for (int c = 0; c < 3; ++c) {
    const int idx = c*256 + lane*4;
    float4 gg = *(const float4*)(g + idx);
    float4 be = *(const float4*)(bb + idx);
    float y0 = (v[c].x - mean)*rstd*gg.x + be.x;
    float y1 = (v[c].y - mean)*rstd*gg.y + be.y;
    float y2 = (v[c].z - mean)*rstd*gg.z + be.z;
    float y3 = (v[c].w - mean)*rstd*gg.w + be.w;
    unsigned r0 = (unsigned)f2bf(y0) | ((unsigned)f2bf(y1) << 16);
    unsigned r1 = (unsigned)f2bf(y2) | ((unsigned)f2bf(y3) << 16);
    *(uint2*)(out + (long)row*DIM + idx) = make_uint2(r0, r1);
  }
}

// ---- generic bf16 GEMM: C[M,N] = A[M,K] @ B[N,K]^T + bias (+act)(+res) ----
// m97-style 128x128 tile, BK=32, reg-staged LDS (safe variant).
template<int ACT, bool HAS_RES, bool OUT_F32, bool OUT_BF16>
__global__ __launch_bounds__(256, 2) void gemm_bt(
    const u16* __restrict__ A, const u16* __restrict__ Bm,
    const float* __restrict__ bias, const float* __restrict__ res,
    float* __restrict__ Cf, u16* __restrict__ Cb,
    int ldc, int M, int N, int K)
{
  __shared__ __align__(16) u16 lA[128*32];
  __shared__ __align__(16) u16 lB[128*32];
  const int tid  = threadIdx.x;
  const int lane = tid & 63;
  const int wave = tid >> 6;
  const int m0 = blockIdx.y * 128;
  const int n0 = blockIdx.x * 128;
  const int fr = lane & 15, fg = lane >> 4;
  const int wr = wave >> 1, wc = wave & 1;
  const int srow = tid >> 2;          // 0..63
  const int scol = (tid & 3) * 8;     // 0,8,16,24

  const int ra0 = (m0 + srow      < M) ? (m0 + srow)      : (M - 1);
  const int ra1 = (m0 + 64 + srow < M) ? (m0 + 64 + srow) : (M - 1);
  const u16* pa0 = A  + (long)ra0 * K + scol;
  const u16* pa1 = A  + (long)ra1 * K + scol;
  const u16* pb0 = Bm + (long)(n0 + srow) * K + scol;        // N is a multiple of 128
  const u16* pb1 = Bm + (long)(n0 + 64 + srow) * K + scol;

  f32x4 acc[4][4] = {};

  for (int kt = 0; kt < K; kt += 32) {
    uint4 va0 = *(const uint4*)(pa0 + kt);
    uint4 va1 = *(const uint4*)(pa1 + kt);
    uint4 vb0 = *(const uint4*)(pb0 + kt);
    uint4 vb1 = *(const uint4*)(pb1 + kt);
    __syncthreads();                       // prior reads done before overwrite
    *(uint4*)&lA[srow*32 + scol]        = va0;
    *(uint4*)&lA[(64 + srow)*32 + scol] = va1;
    *(uint4*)&lB[srow*32 + scol]        = vb0;
    *(uint4*)&lB[(64 + srow)*32 + scol] = vb1;
    __syncthreads();                       // writes visible
    s16x8 af[4], bfr[4];
#pragma unroll
    for (int m = 0; m < 4; ++m) af[m]  = *(const s16x8*)&lA[(wr*64 + m*16 + fr)*32 + fg*8];
#pragma unroll
    for (int n = 0; n < 4; ++n) bfr[n] = *(const s16x8*)&lB[(wc*64 + n*16 + fr)*32 + fg*8];
#pragma unroll
    for (int m = 0; m < 4; ++m)
#pragma unroll
      for (int n = 0; n < 4; ++n)
        acc[m][n] = mfma16(af[m], bfr[n], acc[m][n]);
  }

#pragma unroll
  for (int m = 0; m < 4; ++m) {
#pragma unroll
    for (int n = 0; n < 4; ++n) {
      const int col = n0 + wc*64 + n*16 + fr;
      const float bv = bias[col];
#pragma unroll
      for (int r = 0; r < 4; ++r) {
        const int row = m0 + wr*64 + m*16 + fg*4 + r;
        if (row < M) {
          float v = acc[m][n][r] + bv;
          if constexpr (ACT == 1) v = 0.5f * v * (1.0f + erff(v * 0.70710678118654752f));
          if constexpr (HAS_RES) v += res[(long)row * N + col];
          if constexpr (OUT_F32) Cf[(long)row * ldc + col] = v;
          if constexpr (OUT_BF16) Cb[(long)row * ldc + col] = f2bf(v);
        }
      }
    }
  }
}

// ---- attention: one WG (4 waves) per (b,h). qkv bf16 [TOK][2304] -> o bf16 [TOK][768] ----
__global__ __launch_bounds__(256, 2) void attn(const u16* __restrict__ qkv, u16* __restrict__ o) {
  __shared__ __align__(16) u16 Vt[64][232];        // V transposed (d-major), padded stride
  __shared__ __align__(16) u16 Pl[4][16][232];     // per-wave P tile
  const int bh = blockIdx.x;
  const int b = bh / NHEAD, h = bh - b * NHEAD;
  const int tid = threadIdx.x, lane = tid & 63, wave = tid >> 6;
  const long rbase = (long)b * SEQ * 2304;

  for (int i = tid; i < 224*64; i += 256) {
    const int s = i >> 6, d = i & 63;
    u16 val = 0;
    if (s < SEQ) val = qkv[rbase + (long)s*2304 + 1536 + h*HDK + d];
    Vt[d][s] = val;
  }
  for (int i = lane; i < 16*24; i += 64) {         // zero P pad cols 208..231
    Pl[wave][i / 24][208 + i % 24] = 0;
  }
  __syncthreads();

  const int fr = lane & 15, fg = lane >> 4;
  for (int qb = wave; qb < 13; qb += 4) {
    const int q0 = qb * 16;
    int qrow = q0 + fr; if (qrow > SEQ-1) qrow = SEQ-1;
    const u16* qp = qkv + rbase + (long)qrow*2304 + h*HDK;
    const s16x8 a0 = *(const s16x8*)(qp + fg*8);
    const s16x8 a1 = *(const s16x8*)(qp + 32 + fg*8);
    f32x4 sc[13];
    for (int kb = 0; kb < 13; ++kb) {
      int krow = kb*16 + fr; if (krow > SEQ-1) krow = SEQ-1;
      const u16* kp = qkv + rbase + (long)krow*2304 + DIM + h*HDK;
      const s16x8 b0 = *(const s16x8*)(kp + fg*8);
      const s16x8 b1 = *(const s16x8*)(kp + 32 + fg*8);
      f32x4 c = {0.f, 0.f, 0.f, 0.f};
      c = mfma16(a0, b0, c);
      c = mfma16(a1, b1, c);
      sc[kb] = c;
    }
    float inv[4];
#pragma unroll
    for (int r = 0; r < 4; ++r) {
      float mx = -3e38f;
      for (int kb = 0; kb < 13; ++kb) {
        const int col = kb*16 + fr;
        const float sv = sc[kb][r] * 0.125f;
        sc[kb][r] = sv;
        if (col < SEQ) mx = fmaxf(mx, sv);
      }
#pragma unroll
      for (int off = 1; off < 16; off <<= 1) mx = fmaxf(mx, __shfl_xor(mx, off));
      float sum = 0.f;
      for (int kb = 0; kb < 13; ++kb) {
        const int col = kb*16 + fr;
        const float p = (col < SEQ) ? __expf(sc[kb][r] - mx) : 0.f;
        sc[kb][r] = p;
        sum += p;
      }
#pragma unroll
      for (int off = 1; off < 16; off <<= 1) sum += __shfl_xor(sum, off);
      inv[r] = 1.f / sum;
    }
    asm volatile("s_waitcnt lgkmcnt(0)" ::: "memory");  // prior PV reads done before overwrite
    for (int kb = 0; kb < 13; ++kb) {
      const int col = kb*16 + fr;
#pragma unroll
      for (int r = 0; r < 4; ++r) Pl[wave][fg*4 + r][col] = f2bf(sc[kb][r]);
    }
    asm volatile("s_waitcnt lgkmcnt(0)" ::: "memory");  // P writes visible to whole wave
    for (int nb = 0; nb < 4; ++nb) {
      f32x4 acc = {0.f, 0.f, 0.f, 0.f};
#pragma unroll
      for (int kc = 0; kc < 7; ++kc) {
        const s16x8 pa = *(const s16x8*)&Pl[wave][fr][kc*32 + fg*8];
        const s16x8 vb = *(const s16x8*)&Vt[nb*16 + fr][kc*32 + fg*8];
        acc = mfma16(pa, vb, acc);
      }
#pragma unroll
      for (int r = 0; r < 4; ++r) {
        const int qr = q0 + fg*4 + r;
        if (qr < SEQ) o[((long)b*SEQ + qr)*DIM + h*HDK + nb*16 + fr] = f2bf(acc[r] * inv[r]);
      }
    }
  }
}

// ---- router finalize: LN(512)+silu+r2 matvec+argmax -> idx per token. 1 wave/token ----
__global__ __launch_bounds__(64) void router_fin(
    const float* __restrict__ t1, const float* __restrict__ rg, const float* __restrict__ rb,
    const float* __restrict__ r2w, const float* __restrict__ r2b, int* __restrict__ idxb)
{
  const int t = blockIdx.x;
  const int lane = threadIdx.x;
  const float* row = t1 + (long)t * RH_D;
  float v[8];
  float s = 0.f, s2 = 0.f;
#pragma unroll
  for (int c = 0; c < 2; ++c) {
    float4 u = *(const float4*)(row + lane*8 + c*4);
    v[c*4+0]=u.x; v[c*4+1]=u.y; v[c*4+2]=u.z; v[c*4+3]=u.w;
    s += u.x+u.y+u.z+u.w;
    s2 += u.x*u.x+u.y*u.y+u.z*u.z+u.w*u.w;
  }
#pragma unroll
  for (int o = 1; o < 64; o <<= 1) { s += __shfl_xor(s, o); s2 += __shfl_xor(s2, o); }
  const float mean = s * (1.f/RH_D);
  const float var  = s2 * (1.f/RH_D) - mean*mean;
  const float rstd = rsqrtf(fmaxf(var, 0.f) + 1e-5f);
  float p[4] = {0.f, 0.f, 0.f, 0.f};
#pragma unroll
  for (int i = 0; i < 8; ++i) {
    const int col = lane*8 + i;
    float z = (v[i] - mean)*rstd*rg[col] + rb[col];
    z = z / (1.f + __expf(-z));        // silu
#pragma unroll
    for (int o = 0; o < 4; ++o) p[o] += z * r2w[o*RH_D + col];
  }
#pragma unroll
  for (int o = 0; o < 4; ++o)
#pragma unroll
    for (int off = 1; off < 64; off <<= 1) p[o] += __shfl_xor(p[o], off);
  if (lane == 0) {
    const float l0 = p[0]+r2b[0], l1 = p[1]+r2b[1], l2 = p[2]+r2b[2], l3 = p[3]+r2b[3];
    int b0 = (l1 > l0) ? 1 : 0;
    int b1 = (l3 > l2) ? 1 : 0;
    if (t % SEQ < 1) { b0 = 1; b1 = 1; }   // RES=1 reserved token -> full-one key
    idxb[t] = b0*2 + b1;
  }
}

// ---- routed LoRA expert (gather; identity key exits immediately) ----
__global__ __launch_bounds__(256) void expert_apply(
    const int* __restrict__ idxb, const float* __restrict__ eA,
    const float* __restrict__ eB, float* __restrict__ out)
{
  const int t = blockIdx.x;
  const int e = idxb[t];
  if (e >= NEXP) return;
  __shared__ float xr[DIM];
  __shared__ float dn[RANK_D];
  const int tid = threadIdx.x;
  for (int i = tid; i < DIM; i += 256) xr[i] = out[(long)t*DIM + i];
  __syncthreads();
  {
    const float* ar = eA + ((long)e*RANK_D + tid)*DIM;
    float acc = 0.f;
    for (int k = 0; k < DIM; ++k) acc += ar[k]*xr[k];
    dn[tid] = acc;
  }
  __syncthreads();
  for (int d = tid; d < DIM; d += 256) {
    const float* br = eB + ((long)e*DIM + d)*RANK_D;
    float acc = 0.f;
    for (int r = 0; r < RANK_D; ++r) acc += br[r]*dn[r];
    out[(long)t*DIM + d] += acc;
  }
}

extern "C" void kernel_launch(void* const* d_in, const int* in_sizes, int n_in,
                              void* d_out, int out_size, void* d_ws, size_t ws_size,
                              hipStream_t stream) {
  (void)in_sizes; (void)n_in; (void)out_size;
  const float* x     = (const float*)d_in[0];
  const float* wq_w  = (const float*)d_in[2];
  const float* wq_b  = (const float*)d_in[3];
  const float* wk_w  = (const float*)d_in[4];
  const float* wk_b  = (const float*)d_in[5];
  const float* wv_w  = (const float*)d_in[6];
  const float* wv_b  = (const float*)d_in[7];
  const float* wo_w  = (const float*)d_in[8];
  const float* wo_b  = (const float*)d_in[9];
  const float* an_g  = (const float*)d_in[10];
  const float* an_b  = (const float*)d_in[11];
  const float* fc1_w = (const float*)d_in[12];
  const float* fc1_b = (const float*)d_in[13];
  const float* fc2_w = (const float*)d_in[14];
  const float* fc2_b = (const float*)d_in[15];
  const float* fn_g  = (const float*)d_in[16];
  const float* fn_b  = (const float*)d_in[17];
  const float* r1_w  = (const float*)d_in[18];
  const float* r1_b  = (const float*)d_in[19];
  const float* rn_g  = (const float*)d_in[20];
  const float* rn_b  = (const float*)d_in[21];
  const float* r2_w  = (const float*)d_in[22];
  const float* r2_b  = (const float*)d_in[23];
  const float* eA    = (const float*)d_in[24];
  const float* eB    = (const float*)d_in[25];
  float* outf = (float*)d_out;

  const size_t MiB = 1048576;
  const size_t NEED = 112*MiB + (size_t)TOK*DIM*2;
  if (ws_size < NEED) return;   // leaves d_out poisoned -> readable failure

  char* ws = (char*)d_ws;
  // weights region (0..16MiB)
  u16*   Wqkv = (u16*)(ws + 0);                    // [2304][768]
  u16*   Wo   = (u16*)(ws + 3538944);              // [768][768]
  u16*   Wfc1 = (u16*)(ws + 4718592);              // [3072][768]
  u16*   Wfc2 = (u16*)(ws + 9437184);              // [768][3072]
  u16*   Wr1  = (u16*)(ws + 14155776);             // [512][768]
  float* qkvb = (float*)(ws + 14942208);           // [2304]
  int*   idxb = (int*)(ws + 14952448);             // [TOK]
  // activation slots
  char* SX = ws + 16*MiB;     // x_b16 -> qkv_b16 -> m1 chunk   (56 MiB)
  char* SY = ws + 72*MiB;     // t1 -> x1                        (40 MiB)
  char* SZ = ws + 112*MiB;    // h_b16 -> o_b16 -> h1_b16        (20 MiB)
  u16*   x_b = (u16*)SX;
  u16*   qkv = (u16*)SX;
  u16*   m1  = (u16*)SX;
  float* t1  = (float*)SY;
  float* x1  = (float*)SY;
  u16*   h_b = (u16*)SZ;
  u16*   ob  = (u16*)SZ;
  u16*   h1  = (u16*)SZ;

  // ---- weight + input conversions ----
  cvt_bf16<<<512, 256, 0, stream>>>(wq_w, Wqkv,               589824);
  cvt_bf16<<<512, 256, 0, stream>>>(wk_w, Wqkv + 589824,      589824);
  cvt_bf16<<<512, 256, 0, stream>>>(wv_w, Wqkv + 2*589824,    589824);
  cvt_bf16<<<512, 256, 0, stream>>>(wo_w, Wo,                 589824);
  cvt_bf16<<<1024, 256, 0, stream>>>(fc1_w, Wfc1,             2359296);
  cvt_bf16<<<1024, 256, 0, stream>>>(fc2_w, Wfc2,             2359296);
  cvt_bf16<<<512, 256, 0, stream>>>(r1_w, Wr1,                393216);
  cvt_bf16<<<2048, 256, 0, stream>>>(x, x_b,                  (long)TOK*DIM);
  concat3<<<3, 256, 0, stream>>>(wq_b, wk_b, wv_b, qkvb);

  // ---- router: t1 = x @ r1_w^T + r1_b (f32), then LN+silu+r2+argmax ----
  gemm_bt<0, false, true, false><<<dim3(4, 99), 256, 0, stream>>>(
      x_b, Wr1, r1_b, nullptr, t1, nullptr, RH_D, TOK, RH_D, DIM);
  router_fin<<<TOK, 64, 0, stream>>>(t1, rn_g, rn_b, r2_w, r2_b, idxb);

  // ---- attention ----
  ln_rows<<<TOK/4, 256, 0, stream>>>(x, an_g, an_b, h_b, TOK);
  gemm_bt<0, false, false, true><<<dim3(18, 99), 256, 0, stream>>>(
      h_b, Wqkv, qkvb, nullptr, nullptr, qkv, 3*DIM, TOK, 3*DIM, DIM);
  attn<<<B_SZ*NHEAD, 256, 0, stream>>>(qkv, ob);
  gemm_bt<0, true, true, false><<<dim3(6, 99), 256, 0, stream>>>(
      ob, Wo, wo_b, x, x1, nullptr, DIM, TOK, DIM, DIM);

  // ---- FFN (chunked over M to bound scratch) ----
  ln_rows<<<TOK/4, 256, 0, stream>>>(x1, fn_g, fn_b, h1, TOK);
  for (int c = 0; c < 2; ++c) {
    const int r0 = c * (TOK/2);
    gemm_bt<1, false, false, true><<<dim3(24, 50), 256, 0, stream>>>(
        h1 + (long)r0*DIM, Wfc1, fc1_b, nullptr, nullptr, m1, MLP_D, TOK/2, MLP_D, DIM);
    gemm_bt<0, true, true, false><<<dim3(6, 50), 256, 0, stream>>>(
        m1, Wfc2, fc2_b, x1 + (long)r0*DIM, outf + (long)r0*DIM, nullptr, DIM, TOK/2, DIM, MLP_D);
  }

  // ---- routed LoRA experts (identity for key 3) ----
  expert_apply<<<TOK, 256, 0, stream>>>(idxb, eA, eB, outf);
}

// Round 4
// 548.528 us; speedup vs baseline: 1.0784x; 1.0784x over previous
//
#include <hip/hip_runtime.h>
#include <cstdint>

// ---- problem constants ----
#define B_SZ   64
#define SEQ    197
#define DIM    768
#define NHEAD  12
#define HDK    64
#define MLP_D  3072
#define RH_D   512
#define RANK_D 256
#define NEXP   3
#define TOK    (B_SZ*SEQ)   // 12608

typedef unsigned short u16;
typedef __attribute__((ext_vector_type(8))) short s16x8;
typedef __attribute__((ext_vector_type(4))) float f32x4;

static __device__ __forceinline__ u16 f2bf(float f) {
  unsigned u = __builtin_bit_cast(unsigned, f);
  u = u + 0x7FFFu + ((u >> 16) & 1u);
  return (u16)(u >> 16);
}

static __device__ __forceinline__ f32x4 mfma16(s16x8 a, s16x8 b, f32x4 c) {
  return __builtin_amdgcn_mfma_f32_16x16x32_bf16(a, b, c, 0, 0, 0);
}

// async global->LDS, 16B per lane; LDS dest must be wave-uniform base + lane*16
static __device__ __forceinline__ void gload16(const u16* g, u16* l) {
  __builtin_amdgcn_global_load_lds(
      (const __attribute__((address_space(1))) unsigned int*)(const void*)g,
      (__attribute__((address_space(3))) unsigned int*)(void*)l,
      16, 0, 0);
}

// ---- f32 -> bf16 convert (vector x4) ----
__global__ void cvt_bf16(const float* __restrict__ in, u16* __restrict__ out, long n) {
  long i = ((long)blockIdx.x * blockDim.x + threadIdx.x) * 4;
  const long stride = (long)gridDim.x * blockDim.x * 4;
  for (; i < n; i += stride) {
    float4 v = *(const float4*)(in + i);
    unsigned r0 = (unsigned)f2bf(v.x) | ((unsigned)f2bf(v.y) << 16);
    unsigned r1 = (unsigned)f2bf(v.z) | ((unsigned)f2bf(v.w) << 16);
    *(uint2*)(out + i) = make_uint2(r0, r1);
  }
}

__global__ void concat3(const float* __restrict__ a, const float* __restrict__ b,
                        const float* __restrict__ c, float* __restrict__ out) {
  int i = blockIdx.x * 256 + threadIdx.x;
  if (i < DIM) { out[i] = a[i]; out[DIM + i] = b[i]; out[2*DIM + i] = c[i]; }
}

// ---- LayerNorm over D=768, f32 in -> bf16 out. 4 rows/block (wave per row) ----
__global__ __launch_bounds__(256) void ln_rows(
    const float* __restrict__ x, const float* __restrict__ g,
    const float* __restrict__ bb, u16* __restrict__ out, int M)
{
  const int row = blockIdx.x * 4 + (threadIdx.x >> 6);
  const int lane = threadIdx.x & 63;
  if (row >= M) return;
  const float* xr = x + (long)row * DIM;
  float4 v[3];
  float s = 0.f, s2 = 0.f;
#pragma unroll
  for (int c = 0; c < 3; ++c) {
    v[c] = *(const float4*)(xr + c*256 + lane*4);
    s  += v[c].x + v[c].y + v[c].z + v[c].w;
    s2 += v[c].x*v[c].x + v[c].y*v[c].y + v[c].z*v[c].z + v[c].w*v[c].w;
  }
#pragma unroll
  for (int o = 1; o < 64; o <<= 1) { s += __shfl_xor(s, o); s2 += __shfl_xor(s2, o); }
  const float mean = s * (1.f/DIM);
  const float var  = s2 * (1.f/DIM) - mean*mean;
  const float rstd = rsqrtf(fmaxf(var, 0.f) + 1e-5f);
#pragma unroll
  for (int c = 0; c < 3; ++c) {
    const int idx = c*256 + lane*4;
    float4 gg = *(const float4*)(g + idx);
    float4 be = *(const float4*)(bb + idx);
    float y0 = (v[c].x - mean)*rstd*gg.x + be.x;
    float y1 = (v[c].y - mean)*rstd*gg.y + be.y;
    float y2 = (v[c].z - mean)*rstd*gg.z + be.z;
    float y3 = (v[c].w - mean)*rstd*gg.w + be.w;
    unsigned r0 = (unsigned)f2bf(y0) | ((unsigned)f2bf(y1) << 16);
    unsigned r1 = (unsigned)f2bf(y2) | ((unsigned)f2bf(y3) << 16);
    *(uint2*)(out + (long)row*DIM + idx) = make_uint2(r0, r1);
  }
}

// ---- generic bf16 GEMM: C[M,N] = A[M,K] @ B[N,K]^T + bias (+act)(+res) ----
// m97-style: 128x128 tile, BK=32, global_load_lds(16B) staging, 2-barrier loop.
template<int ACT, bool HAS_RES, bool OUT_F32, bool OUT_BF16>
__global__ __launch_bounds__(256) void gemm_bt(
    const u16* __restrict__ A, const u16* __restrict__ Bm,
    const float* __restrict__ bias, const float* __restrict__ res,
    float* __restrict__ Cf, u16* __restrict__ Cb,
    int ldc, int M, int N, int K)
{
  __shared__ __align__(16) u16 lA[128*32];
  __shared__ __align__(16) u16 lB[128*32];
  const int tid  = threadIdx.x;
  const int lane = tid & 63;
  const int wave = tid >> 6;
  const int m0 = blockIdx.y * 128;
  const int n0 = blockIdx.x * 128;
  const int fr = lane & 15, fg = lane >> 4;
  const int wr = wave >> 1, wc = wave & 1;
  const int srow = tid >> 2;          // 0..63
  const int scol = (tid & 3) * 8;     // 0,8,16,24  -> LDS byte offset == tid*16 (linear)

  const int ra0 = (m0 + srow      < M) ? (m0 + srow)      : (M - 1);
  const int ra1 = (m0 + 64 + srow < M) ? (m0 + 64 + srow) : (M - 1);
  const u16* pa0 = A  + (long)ra0 * K + scol;
  const u16* pa1 = A  + (long)ra1 * K + scol;
  const u16* pb0 = Bm + (long)(n0 + srow) * K + scol;        // N is a multiple of 128
  const u16* pb1 = Bm + (long)(n0 + 64 + srow) * K + scol;
  u16* dstA0 = &lA[srow*32 + scol];
  u16* dstA1 = &lA[(64 + srow)*32 + scol];
  u16* dstB0 = &lB[srow*32 + scol];
  u16* dstB1 = &lB[(64 + srow)*32 + scol];

  f32x4 acc[4][4] = {};

  for (int kt = 0; kt < K; kt += 32) {
    __syncthreads();                       // prior tile fully consumed
    gload16(pa0 + kt, dstA0);
    gload16(pa1 + kt, dstA1);
    gload16(pb0 + kt, dstB0);
    gload16(pb1 + kt, dstB1);
    __syncthreads();                       // vmcnt(0) drained by compiler before barrier
    s16x8 af[4], bfr[4];
#pragma unroll
    for (int m = 0; m < 4; ++m) af[m]  = *(const s16x8*)&lA[(wr*64 + m*16 + fr)*32 + fg*8];
#pragma unroll
    for (int n = 0; n < 4; ++n) bfr[n] = *(const s16x8*)&lB[(wc*64 + n*16 + fr)*32 + fg*8];
#pragma unroll
    for (int m = 0; m < 4; ++m)
#pragma unroll
      for (int n = 0; n < 4; ++n)
        acc[m][n] = mfma16(af[m], bfr[n], acc[m][n]);
  }

#pragma unroll
  for (int m = 0; m < 4; ++m) {
#pragma unroll
    for (int n = 0; n < 4; ++n) {
      const int col = n0 + wc*64 + n*16 + fr;
      const float bv = bias[col];
#pragma unroll
      for (int r = 0; r < 4; ++r) {
        const int row = m0 + wr*64 + m*16 + fg*4 + r;
        if (row < M) {
          float v = acc[m][n][r] + bv;
          if constexpr (ACT == 1) v = 0.5f * v * (1.0f + erff(v * 0.70710678118654752f));
          if constexpr (HAS_RES) v += res[(long)row * N + col];
          if constexpr (OUT_F32) Cf[(long)row * ldc + col] = v;
          if constexpr (OUT_BF16) Cb[(long)row * ldc + col] = f2bf(v);
        }
      }
    }
  }
}

// ---- attention: one WG (4 waves) per (b,h). qkv bf16 [TOK][2304] -> o bf16 [TOK][768] ----
__global__ __launch_bounds__(256, 2) void attn(const u16* __restrict__ qkv, u16* __restrict__ o) {
  __shared__ __align__(16) u16 Vt[64][232];        // V transposed (d-major), padded stride
  __shared__ __align__(16) u16 Pl[4][16][232];     // per-wave P tile
  const int bh = blockIdx.x;
  const int b = bh / NHEAD, h = bh - b * NHEAD;
  const int tid = threadIdx.x, lane = tid & 63, wave = tid >> 6;
  const long rbase = (long)b * SEQ * 2304;

  for (int i = tid; i < 224*64; i += 256) {
    const int s = i >> 6, d = i & 63;
    u16 val = 0;
    if (s < SEQ) val = qkv[rbase + (long)s*2304 + 1536 + h*HDK + d];
    Vt[d][s] = val;
  }
  for (int i = lane; i < 16*24; i += 64) {         // zero P pad cols 208..231
    Pl[wave][i / 24][208 + i % 24] = 0;
  }
  __syncthreads();

  const int fr = lane & 15, fg = lane >> 4;
  for (int qb = wave; qb < 13; qb += 4) {
    const int q0 = qb * 16;
    int qrow = q0 + fr; if (qrow > SEQ-1) qrow = SEQ-1;
    const u16* qp = qkv + rbase + (long)qrow*2304 + h*HDK;
    const s16x8 a0 = *(const s16x8*)(qp + fg*8);
    const s16x8 a1 = *(const s16x8*)(qp + 32 + fg*8);
    f32x4 sc[13];
    for (int kb = 0; kb < 13; ++kb) {
      int krow = kb*16 + fr; if (krow > SEQ-1) krow = SEQ-1;
      const u16* kp = qkv + rbase + (long)krow*2304 + DIM + h*HDK;
      const s16x8 b0 = *(const s16x8*)(kp + fg*8);
      const s16x8 b1 = *(const s16x8*)(kp + 32 + fg*8);
      f32x4 c = {0.f, 0.f, 0.f, 0.f};
      c = mfma16(a0, b0, c);
      c = mfma16(a1, b1, c);
      sc[kb] = c;
    }
    float inv[4];
#pragma unroll
    for (int r = 0; r < 4; ++r) {
      float mx = -3e38f;
      for (int kb = 0; kb < 13; ++kb) {
        const int col = kb*16 + fr;
        const float sv = sc[kb][r] * 0.125f;
        sc[kb][r] = sv;
        if (col < SEQ) mx = fmaxf(mx, sv);
      }
#pragma unroll
      for (int off = 1; off < 16; off <<= 1) mx = fmaxf(mx, __shfl_xor(mx, off));
      float sum = 0.f;
      for (int kb = 0; kb < 13; ++kb) {
        const int col = kb*16 + fr;
        const float p = (col < SEQ) ? __expf(sc[kb][r] - mx) : 0.f;
        sc[kb][r] = p;
        sum += p;
      }
#pragma unroll
      for (int off = 1; off < 16; off <<= 1) sum += __shfl_xor(sum, off);
      inv[r] = 1.f / sum;
    }
    asm volatile("s_waitcnt lgkmcnt(0)" ::: "memory");  // prior PV reads done before overwrite
    for (int kb = 0; kb < 13; ++kb) {
      const int col = kb*16 + fr;
#pragma unroll
      for (int r = 0; r < 4; ++r) Pl[wave][fg*4 + r][col] = f2bf(sc[kb][r]);
    }
    asm volatile("s_waitcnt lgkmcnt(0)" ::: "memory");  // P writes visible to whole wave
    for (int nb = 0; nb < 4; ++nb) {
      f32x4 acc = {0.f, 0.f, 0.f, 0.f};
#pragma unroll
      for (int kc = 0; kc < 7; ++kc) {
        const s16x8 pa = *(const s16x8*)&Pl[wave][fr][kc*32 + fg*8];
        const s16x8 vb = *(const s16x8*)&Vt[nb*16 + fr][kc*32 + fg*8];
        acc = mfma16(pa, vb, acc);
      }
#pragma unroll
      for (int r = 0; r < 4; ++r) {
        const int qr = q0 + fg*4 + r;
        if (qr < SEQ) o[((long)b*SEQ + qr)*DIM + h*HDK + nb*16 + fr] = f2bf(acc[r] * inv[r]);
      }
    }
  }
}

// ---- router finalize: LN(512)+silu+r2 matvec+argmax -> idx per token. 1 wave/token ----
__global__ __launch_bounds__(64) void router_fin(
    const float* __restrict__ t1, const float* __restrict__ rg, const float* __restrict__ rb,
    const float* __restrict__ r2w, const float* __restrict__ r2b, int* __restrict__ idxb)
{
  const int t = blockIdx.x;
  const int lane = threadIdx.x;
  const float* row = t1 + (long)t * RH_D;
  float v[8];
  float s = 0.f, s2 = 0.f;
#pragma unroll
  for (int c = 0; c < 2; ++c) {
    float4 u = *(const float4*)(row + lane*8 + c*4);
    v[c*4+0]=u.x; v[c*4+1]=u.y; v[c*4+2]=u.z; v[c*4+3]=u.w;
    s += u.x+u.y+u.z+u.w;
    s2 += u.x*u.x+u.y*u.y+u.z*u.z+u.w*u.w;
  }
#pragma unroll
  for (int o = 1; o < 64; o <<= 1) { s += __shfl_xor(s, o); s2 += __shfl_xor(s2, o); }
  const float mean = s * (1.f/RH_D);
  const float var  = s2 * (1.f/RH_D) - mean*mean;
  const float rstd = rsqrtf(fmaxf(var, 0.f) + 1e-5f);
  float p[4] = {0.f, 0.f, 0.f, 0.f};
#pragma unroll
  for (int i = 0; i < 8; ++i) {
    const int col = lane*8 + i;
    float z = (v[i] - mean)*rstd*rg[col] + rb[col];
    z = z / (1.f + __expf(-z));        // silu
#pragma unroll
    for (int o = 0; o < 4; ++o) p[o] += z * r2w[o*RH_D + col];
  }
#pragma unroll
  for (int o = 0; o < 4; ++o)
#pragma unroll
    for (int off = 1; off < 64; off <<= 1) p[o] += __shfl_xor(p[o], off);
  if (lane == 0) {
    const float l0 = p[0]+r2b[0], l1 = p[1]+r2b[1], l2 = p[2]+r2b[2], l3 = p[3]+r2b[3];
    int b0 = (l1 > l0) ? 1 : 0;
    int b1 = (l3 > l2) ? 1 : 0;
    if (t % SEQ < 1) { b0 = 1; b1 = 1; }   // RES=1 reserved token -> full-one key
    idxb[t] = b0*2 + b1;
  }
}

// ---- routed LoRA expert (gather; identity key exits immediately) ----
__global__ __launch_bounds__(256) void expert_apply(
    const int* __restrict__ idxb, const float* __restrict__ eA,
    const float* __restrict__ eB, float* __restrict__ out)
{
  const int t = blockIdx.x;
  const int e = idxb[t];
  if (e >= NEXP) return;
  __shared__ float xr[DIM];
  __shared__ float dn[RANK_D];
  const int tid = threadIdx.x;
  for (int i = tid; i < DIM; i += 256) xr[i] = out[(long)t*DIM + i];
  __syncthreads();
  {
    const float* ar = eA + ((long)e*RANK_D + tid)*DIM;
    float acc = 0.f;
    for (int k = 0; k < DIM; ++k) acc += ar[k]*xr[k];
    dn[tid] = acc;
  }
  __syncthreads();
  for (int d = tid; d < DIM; d += 256) {
    const float* br = eB + ((long)e*DIM + d)*RANK_D;
    float acc = 0.f;
    for (int r = 0; r < RANK_D; ++r) acc += br[r]*dn[r];
    out[(long)t*DIM + d] += acc;
  }
}

extern "C" void kernel_launch(void* const* d_in, const int* in_sizes, int n_in,
                              void* d_out, int out_size, void* d_ws, size_t ws_size,
                              hipStream_t stream) {
  (void)in_sizes; (void)n_in; (void)out_size;
  const float* x     = (const float*)d_in[0];
  const float* wq_w  = (const float*)d_in[2];
  const float* wq_b  = (const float*)d_in[3];
  const float* wk_w  = (const float*)d_in[4];
  const float* wk_b  = (const float*)d_in[5];
  const float* wv_w  = (const float*)d_in[6];
  const float* wv_b  = (const float*)d_in[7];
  const float* wo_w  = (const float*)d_in[8];
  const float* wo_b  = (const float*)d_in[9];
  const float* an_g  = (const float*)d_in[10];
  const float* an_b  = (const float*)d_in[11];
  const float* fc1_w = (const float*)d_in[12];
  const float* fc1_b = (const float*)d_in[13];
  const float* fc2_w = (const float*)d_in[14];
  const float* fc2_b = (const float*)d_in[15];
  const float* fn_g  = (const float*)d_in[16];
  const float* fn_b  = (const float*)d_in[17];
  const float* r1_w  = (const float*)d_in[18];
  const float* r1_b  = (const float*)d_in[19];
  const float* rn_g  = (const float*)d_in[20];
  const float* rn_b  = (const float*)d_in[21];
  const float* r2_w  = (const float*)d_in[22];
  const float* r2_b  = (const float*)d_in[23];
  const float* eA    = (const float*)d_in[24];
  const float* eB    = (const float*)d_in[25];
  float* outf = (float*)d_out;

  const size_t MiB = 1048576;
  const size_t NEED_FULL = 153*MiB;                       // unchunked FFN (m1 = 77.5 MiB)
  const size_t NEED_MIN  = 112*MiB + (size_t)TOK*DIM*2;   // 2-chunk fallback (round-3 layout)
  if (ws_size < NEED_MIN) return;   // leaves d_out poisoned -> readable failure
  const bool full = (ws_size >= NEED_FULL);
  const int  nc   = full ? 1 : 2;
  const int  MC   = TOK / nc;       // 12608 or 6304
  const size_t offSY = full ? 94*MiB  : 72*MiB;
  const size_t offSZ = full ? 133*MiB : 112*MiB;

  char* ws = (char*)d_ws;
  // weights region (0..16MiB)
  u16*   Wqkv = (u16*)(ws + 0);                    // [2304][768]
  u16*   Wo   = (u16*)(ws + 3538944);              // [768][768]
  u16*   Wfc1 = (u16*)(ws + 4718592);              // [3072][768]
  u16*   Wfc2 = (u16*)(ws + 9437184);              // [768][3072]
  u16*   Wr1  = (u16*)(ws + 14155776);             // [512][768]
  float* qkvb = (float*)(ws + 14942208);           // [2304]
  int*   idxb = (int*)(ws + 14952448);             // [TOK]
  // activation slots
  char* SX = ws + 16*MiB;     // x_b16 -> qkv_b16 -> m1 (full or chunk)
  char* SY = ws + offSY;      // t1 -> x1 (f32)
  char* SZ = ws + offSZ;      // h_b16 -> o_b16 -> h1_b16
  u16*   x_b = (u16*)SX;
  u16*   qkv = (u16*)SX;
  u16*   m1  = (u16*)SX;
  float* t1  = (float*)SY;
  float* x1  = (float*)SY;
  u16*   h_b = (u16*)SZ;
  u16*   ob  = (u16*)SZ;
  u16*   h1  = (u16*)SZ;

  // ---- weight + input conversions ----
  cvt_bf16<<<512, 256, 0, stream>>>(wq_w, Wqkv,               589824);
  cvt_bf16<<<512, 256, 0, stream>>>(wk_w, Wqkv + 589824,      589824);
  cvt_bf16<<<512, 256, 0, stream>>>(wv_w, Wqkv + 2*589824,    589824);
  cvt_bf16<<<512, 256, 0, stream>>>(wo_w, Wo,                 589824);
  cvt_bf16<<<1024, 256, 0, stream>>>(fc1_w, Wfc1,             2359296);
  cvt_bf16<<<1024, 256, 0, stream>>>(fc2_w, Wfc2,             2359296);
  cvt_bf16<<<512, 256, 0, stream>>>(r1_w, Wr1,                393216);
  cvt_bf16<<<2048, 256, 0, stream>>>(x, x_b,                  (long)TOK*DIM);
  concat3<<<3, 256, 0, stream>>>(wq_b, wk_b, wv_b, qkvb);

  // ---- router: t1 = x @ r1_w^T + r1_b (f32), then LN+silu+r2+argmax ----
  gemm_bt<0, false, true, false><<<dim3(4, 99), 256, 0, stream>>>(
      x_b, Wr1, r1_b, nullptr, t1, nullptr, RH_D, TOK, RH_D, DIM);
  router_fin<<<TOK, 64, 0, stream>>>(t1, rn_g, rn_b, r2_w, r2_b, idxb);

  // ---- attention ----
  ln_rows<<<TOK/4, 256, 0, stream>>>(x, an_g, an_b, h_b, TOK);
  gemm_bt<0, false, false, true><<<dim3(18, 99), 256, 0, stream>>>(
      h_b, Wqkv, qkvb, nullptr, nullptr, qkv, 3*DIM, TOK, 3*DIM, DIM);
  attn<<<B_SZ*NHEAD, 256, 0, stream>>>(qkv, ob);
  gemm_bt<0, true, true, false><<<dim3(6, 99), 256, 0, stream>>>(
      ob, Wo, wo_b, x, x1, nullptr, DIM, TOK, DIM, DIM);

  // ---- FFN (full-M if ws allows; else 2 chunks) ----
  ln_rows<<<TOK/4, 256, 0, stream>>>(x1, fn_g, fn_b, h1, TOK);
  for (int c = 0; c < nc; ++c) {
    const int r0 = c * MC;
    const int gy = (MC + 127) / 128;
    gemm_bt<1, false, false, true><<<dim3(24, gy), 256, 0, stream>>>(
        h1 + (long)r0*DIM, Wfc1, fc1_b, nullptr, nullptr, m1, MLP_D, MC, MLP_D, DIM);
    gemm_bt<0, true, true, false><<<dim3(6, gy), 256, 0, stream>>>(
        m1, Wfc2, fc2_b, x1 + (long)r0*DIM, outf + (long)r0*DIM, nullptr, DIM, MC, DIM, MLP_D);
  }

  // ---- routed LoRA experts (identity for key 3) ----
  expert_apply<<<TOK, 256, 0, stream>>>(idxb, eA, eB, outf);
}

// Round 5
// 512.432 us; speedup vs baseline: 1.1544x; 1.0704x over previous
//
#include <hip/hip_runtime.h>
#include <cstdint>

// ---- problem constants ----
#define B_SZ   64
#define SEQ    197
#define DIM    768
#define NHEAD  12
#define HDK    64
#define MLP_D  3072
#define RH_D   512
#define RANK_D 256
#define NEXP   3
#define TOK    (B_SZ*SEQ)   // 12608

typedef unsigned short u16;
typedef __attribute__((ext_vector_type(8))) short s16x8;
typedef __attribute__((ext_vector_type(4))) float f32x4;

static __device__ __forceinline__ u16 f2bf(float f) {
  unsigned u = __builtin_bit_cast(unsigned, f);
  u = u + 0x7FFFu + ((u >> 16) & 1u);
  return (u16)(u >> 16);
}

static __device__ __forceinline__ f32x4 mfma16(s16x8 a, s16x8 b, f32x4 c) {
  return __builtin_amdgcn_mfma_f32_16x16x32_bf16(a, b, c, 0, 0, 0);
}

// async global->LDS, 16B per lane; LDS dest must be wave-uniform base + lane*16
static __device__ __forceinline__ void gload16(const u16* g, u16* l) {
  __builtin_amdgcn_global_load_lds(
      (const __attribute__((address_space(1))) unsigned int*)(const void*)g,
      (__attribute__((address_space(3))) unsigned int*)(void*)l,
      16, 0, 0);
}

// fast exact-enough GELU: 0.5x(1+tanh(u)) == x*sigmoid(2u), |err| <= ~3e-4
static __device__ __forceinline__ float gelu_fast(float v) {
  const float u2 = 2.f * v * (0.7978845608f + 0.0356774081f * v * v);
  return v / (1.f + __expf(-u2));
}

// ---- f32 -> bf16 convert (vector x4) ----
__global__ void cvt_bf16(const float* __restrict__ in, u16* __restrict__ out, long n) {
  long i = ((long)blockIdx.x * blockDim.x + threadIdx.x) * 4;
  const long stride = (long)gridDim.x * blockDim.x * 4;
  for (; i < n; i += stride) {
    float4 v = *(const float4*)(in + i);
    unsigned r0 = (unsigned)f2bf(v.x) | ((unsigned)f2bf(v.y) << 16);
    unsigned r1 = (unsigned)f2bf(v.z) | ((unsigned)f2bf(v.w) << 16);
    *(uint2*)(out + i) = make_uint2(r0, r1);
  }
}

__global__ void concat3(const float* __restrict__ a, const float* __restrict__ b,
                        const float* __restrict__ c, float* __restrict__ out) {
  int i = blockIdx.x * 256 + threadIdx.x;
  if (i < DIM) { out[i] = a[i]; out[DIM + i] = b[i]; out[2*DIM + i] = c[i]; }
}

// ---- LayerNorm over D=768, f32 in -> bf16 out. 4 rows/block (wave per row) ----
__global__ __launch_bounds__(256) void ln_rows(
    const float* __restrict__ x, const float* __restrict__ g,
    const float* __restrict__ bb, u16* __restrict__ out, int M)
{
  const int row = blockIdx.x * 4 + (threadIdx.x >> 6);
  const int lane = threadIdx.x & 63;
  if (row >= M) return;
  const float* xr = x + (long)row * DIM;
  float4 v[3];
  float s = 0.f, s2 = 0.f;
#pragma unroll
  for (int c = 0; c < 3; ++c) {
    v[c] = *(const float4*)(xr + c*256 + lane*4);
    s  += v[c].x + v[c].y + v[c].z + v[c].w;
    s2 += v[c].x*v[c].x + v[c].y*v[c].y + v[c].z*v[c].z + v[c].w*v[c].w;
  }
#pragma unroll
  for (int o = 1; o < 64; o <<= 1) { s += __shfl_xor(s, o); s2 += __shfl_xor(s2, o); }
  const float mean = s * (1.f/DIM);
  const float var  = s2 * (1.f/DIM) - mean*mean;
  const float rstd = rsqrtf(fmaxf(var, 0.f) + 1e-5f);
#pragma unroll
  for (int c = 0; c < 3; ++c) {
    const int idx = c*256 + lane*4;
    float4 gg = *(const float4*)(g + idx);
    float4 be = *(const float4*)(bb + idx);
    float y0 = (v[c].x - mean)*rstd*gg.x + be.x;
    float y1 = (v[c].y - mean)*rstd*gg.y + be.y;
    float y2 = (v[c].z - mean)*rstd*gg.z + be.z;
    float y3 = (v[c].w - mean)*rstd*gg.w + be.w;
    unsigned r0 = (unsigned)f2bf(y0) | ((unsigned)f2bf(y1) << 16);
    unsigned r1 = (unsigned)f2bf(y2) | ((unsigned)f2bf(y3) << 16);
    *(uint2*)(out + (long)row*DIM + idx) = make_uint2(r0, r1);
  }
}

// ---- generic bf16 GEMM: C[M,N] = A[M,K] @ B[N,K]^T + bias (+act)(+res) ----
// 128x128 tile, BK=32, global_load_lds(16B) staging, depth-1 pipelined
// double-buffer: issue next-tile loads BEFORE current compute, one barrier/step.
template<int ACT, bool HAS_RES, bool OUT_F32, bool OUT_BF16>
__global__ __launch_bounds__(256) void gemm_bt(
    const u16* __restrict__ A, const u16* __restrict__ Bm,
    const float* __restrict__ bias, const float* __restrict__ res,
    float* __restrict__ Cf, u16* __restrict__ Cb,
    int ldc, int M, int N, int K)
{
  __shared__ __align__(16) u16 lA[2][128*32];
  __shared__ __align__(16) u16 lB[2][128*32];
  const int tid  = threadIdx.x;
  const int lane = tid & 63;
  const int wave = tid >> 6;
  const int m0 = blockIdx.y * 128;
  const int n0 = blockIdx.x * 128;
  const int fr = lane & 15, fg = lane >> 4;
  const int wr = wave >> 1, wc = wave & 1;
  const int srow = tid >> 2;          // 0..63
  const int scol = (tid & 3) * 8;     // LDS byte offset == tid*16 (linear, gload_lds-safe)

  const int ra0 = (m0 + srow      < M) ? (m0 + srow)      : (M - 1);
  const int ra1 = (m0 + 64 + srow < M) ? (m0 + 64 + srow) : (M - 1);
  const u16* pa0 = A  + (long)ra0 * K + scol;
  const u16* pa1 = A  + (long)ra1 * K + scol;
  const u16* pb0 = Bm + (long)(n0 + srow) * K + scol;        // N is a multiple of 128
  const u16* pb1 = Bm + (long)(n0 + 64 + srow) * K + scol;

  auto STAGE = [&](int buf, int kt) {
    gload16(pa0 + kt, &lA[buf][srow*32 + scol]);
    gload16(pa1 + kt, &lA[buf][(64 + srow)*32 + scol]);
    gload16(pb0 + kt, &lB[buf][srow*32 + scol]);
    gload16(pb1 + kt, &lB[buf][(64 + srow)*32 + scol]);
  };

  f32x4 acc[4][4] = {};

  STAGE(0, 0);
  __syncthreads();                      // drain vmcnt(0): buf0 ready
  int cur = 0;
  const int nsteps = K >> 5;
  for (int t = 0; t < nsteps; ++t) {
    if (t + 1 < nsteps) STAGE(cur ^ 1, (t + 1) << 5);   // issue-early
    s16x8 af[4], bfr[4];
#pragma unroll
    for (int m = 0; m < 4; ++m) af[m]  = *(const s16x8*)&lA[cur][(wr*64 + m*16 + fr)*32 + fg*8];
#pragma unroll
    for (int n = 0; n < 4; ++n) bfr[n] = *(const s16x8*)&lB[cur][(wc*64 + n*16 + fr)*32 + fg*8];
#pragma unroll
    for (int m = 0; m < 4; ++m)
#pragma unroll
      for (int n = 0; n < 4; ++n)
        acc[m][n] = mfma16(af[m], bfr[n], acc[m][n]);
    __syncthreads();                    // drain-late: next tile ready, reads done
    cur ^= 1;
  }

#pragma unroll
  for (int m = 0; m < 4; ++m) {
#pragma unroll
    for (int n = 0; n < 4; ++n) {
      const int col = n0 + wc*64 + n*16 + fr;
      const float bv = bias[col];
#pragma unroll
      for (int r = 0; r < 4; ++r) {
        const int row = m0 + wr*64 + m*16 + fg*4 + r;
        if (row < M) {
          float v = acc[m][n][r] + bv;
          if constexpr (ACT == 1) v = gelu_fast(v);
          if constexpr (HAS_RES) v += res[(long)row * N + col];
          if constexpr (OUT_F32) Cf[(long)row * ldc + col] = v;
          if constexpr (OUT_BF16) Cb[(long)row * ldc + col] = f2bf(v);
        }
      }
    }
  }
}

// ---- attention: one WG (4 waves) per (b,h). qkv bf16 [TOK][2304] -> o bf16 [TOK][768] ----
__global__ __launch_bounds__(256, 2) void attn(const u16* __restrict__ qkv, u16* __restrict__ o) {
  __shared__ __align__(16) u16 Vt[64][232];        // V transposed (d-major), padded stride
  __shared__ __align__(16) u16 Pl[4][16][232];     // per-wave P tile
  const int bh = blockIdx.x;
  const int b = bh / NHEAD, h = bh - b * NHEAD;
  const int tid = threadIdx.x, lane = tid & 63, wave = tid >> 6;
  const long rbase = (long)b * SEQ * 2304;

  for (int i = tid; i < 224*64; i += 256) {
    const int s = i >> 6, d = i & 63;
    u16 val = 0;
    if (s < SEQ) val = qkv[rbase + (long)s*2304 + 1536 + h*HDK + d];
    Vt[d][s] = val;
  }
  for (int i = lane; i < 16*24; i += 64) {         // zero P pad cols 208..231
    Pl[wave][i / 24][208 + i % 24] = 0;
  }
  __syncthreads();

  const int fr = lane & 15, fg = lane >> 4;
  for (int qb = wave; qb < 13; qb += 4) {
    const int q0 = qb * 16;
    int qrow = q0 + fr; if (qrow > SEQ-1) qrow = SEQ-1;
    const u16* qp = qkv + rbase + (long)qrow*2304 + h*HDK;
    const s16x8 a0 = *(const s16x8*)(qp + fg*8);
    const s16x8 a1 = *(const s16x8*)(qp + 32 + fg*8);
    f32x4 sc[13];
    for (int kb = 0; kb < 13; ++kb) {
      int krow = kb*16 + fr; if (krow > SEQ-1) krow = SEQ-1;
      const u16* kp = qkv + rbase + (long)krow*2304 + DIM + h*HDK;
      const s16x8 b0 = *(const s16x8*)(kp + fg*8);
      const s16x8 b1 = *(const s16x8*)(kp + 32 + fg*8);
      f32x4 c = {0.f, 0.f, 0.f, 0.f};
      c = mfma16(a0, b0, c);
      c = mfma16(a1, b1, c);
      sc[kb] = c;
    }
    float inv[4];
#pragma unroll
    for (int r = 0; r < 4; ++r) {
      float mx = -3e38f;
      for (int kb = 0; kb < 13; ++kb) {
        const int col = kb*16 + fr;
        const float sv = sc[kb][r] * 0.125f;
        sc[kb][r] = sv;
        if (col < SEQ) mx = fmaxf(mx, sv);
      }
#pragma unroll
      for (int off = 1; off < 16; off <<= 1) mx = fmaxf(mx, __shfl_xor(mx, off));
      float sum = 0.f;
      for (int kb = 0; kb < 13; ++kb) {
        const int col = kb*16 + fr;
        const float p = (col < SEQ) ? __expf(sc[kb][r] - mx) : 0.f;
        sc[kb][r] = p;
        sum += p;
      }
#pragma unroll
      for (int off = 1; off < 16; off <<= 1) sum += __shfl_xor(sum, off);
      inv[r] = 1.f / sum;
    }
    asm volatile("s_waitcnt lgkmcnt(0)" ::: "memory");  // prior PV reads done before overwrite
    for (int kb = 0; kb < 13; ++kb) {
      const int col = kb*16 + fr;
#pragma unroll
      for (int r = 0; r < 4; ++r) Pl[wave][fg*4 + r][col] = f2bf(sc[kb][r]);
    }
    asm volatile("s_waitcnt lgkmcnt(0)" ::: "memory");  // P writes visible to whole wave
    for (int nb = 0; nb < 4; ++nb) {
      f32x4 acc = {0.f, 0.f, 0.f, 0.f};
#pragma unroll
      for (int kc = 0; kc < 7; ++kc) {
        const s16x8 pa = *(const s16x8*)&Pl[wave][fr][kc*32 + fg*8];
        const s16x8 vb = *(const s16x8*)&Vt[nb*16 + fr][kc*32 + fg*8];
        acc = mfma16(pa, vb, acc);
      }
#pragma unroll
      for (int r = 0; r < 4; ++r) {
        const int qr = q0 + fg*4 + r;
        if (qr < SEQ) o[((long)b*SEQ + qr)*DIM + h*HDK + nb*16 + fr] = f2bf(acc[r] * inv[r]);
      }
    }
  }
}

// ---- router finalize: LN(512)+silu+r2 matvec+argmax -> idx per token. 1 wave/token ----
__global__ __launch_bounds__(64) void router_fin(
    const float* __restrict__ t1, const float* __restrict__ rg, const float* __restrict__ rb,
    const float* __restrict__ r2w, const float* __restrict__ r2b, int* __restrict__ idxb)
{
  const int t = blockIdx.x;
  const int lane = threadIdx.x;
  const float* row = t1 + (long)t * RH_D;
  float v[8];
  float s = 0.f, s2 = 0.f;
#pragma unroll
  for (int c = 0; c < 2; ++c) {
    float4 u = *(const float4*)(row + lane*8 + c*4);
    v[c*4+0]=u.x; v[c*4+1]=u.y; v[c*4+2]=u.z; v[c*4+3]=u.w;
    s += u.x+u.y+u.z+u.w;
    s2 += u.x*u.x+u.y*u.y+u.z*u.z+u.w*u.w;
  }
#pragma unroll
  for (int o = 1; o < 64; o <<= 1) { s += __shfl_xor(s, o); s2 += __shfl_xor(s2, o); }
  const float mean = s * (1.f/RH_D);
  const float var  = s2 * (1.f/RH_D) - mean*mean;
  const float rstd = rsqrtf(fmaxf(var, 0.f) + 1e-5f);
  float p[4] = {0.f, 0.f, 0.f, 0.f};
#pragma unroll
  for (int i = 0; i < 8; ++i) {
    const int col = lane*8 + i;
    float z = (v[i] - mean)*rstd*rg[col] + rb[col];
    z = z / (1.f + __expf(-z));        // silu
#pragma unroll
    for (int o = 0; o < 4; ++o) p[o] += z * r2w[o*RH_D + col];
  }
#pragma unroll
  for (int o = 0; o < 4; ++o)
#pragma unroll
    for (int off = 1; off < 64; off <<= 1) p[o] += __shfl_xor(p[o], off);
  if (lane == 0) {
    const float l0 = p[0]+r2b[0], l1 = p[1]+r2b[1], l2 = p[2]+r2b[2], l3 = p[3]+r2b[3];
    int b0 = (l1 > l0) ? 1 : 0;
    int b1 = (l3 > l2) ? 1 : 0;
    if (t % SEQ < 1) { b0 = 1; b1 = 1; }   // RES=1 reserved token -> full-one key
    idxb[t] = b0*2 + b1;
  }
}

// ---- routed LoRA expert (gather; identity key exits immediately) ----
__global__ __launch_bounds__(256) void expert_apply(
    const int* __restrict__ idxb, const float* __restrict__ eA,
    const float* __restrict__ eB, float* __restrict__ out)
{
  const int t = blockIdx.x;
  const int e = idxb[t];
  if (e >= NEXP) return;
  __shared__ float xr[DIM];
  __shared__ float dn[RANK_D];
  const int tid = threadIdx.x;
  for (int i = tid; i < DIM; i += 256) xr[i] = out[(long)t*DIM + i];
  __syncthreads();
  {
    const float* ar = eA + ((long)e*RANK_D + tid)*DIM;
    float acc = 0.f;
    for (int k = 0; k < DIM; ++k) acc += ar[k]*xr[k];
    dn[tid] = acc;
  }
  __syncthreads();
  for (int d = tid; d < DIM; d += 256) {
    const float* br = eB + ((long)e*DIM + d)*RANK_D;
    float acc = 0.f;
    for (int r = 0; r < RANK_D; ++r) acc += br[r]*dn[r];
    out[(long)t*DIM + d] += acc;
  }
}

extern "C" void kernel_launch(void* const* d_in, const int* in_sizes, int n_in,
                              void* d_out, int out_size, void* d_ws, size_t ws_size,
                              hipStream_t stream) {
  (void)in_sizes; (void)n_in; (void)out_size;
  const float* x     = (const float*)d_in[0];
  const float* wq_w  = (const float*)d_in[2];
  const float* wq_b  = (const float*)d_in[3];
  const float* wk_w  = (const float*)d_in[4];
  const float* wk_b  = (const float*)d_in[5];
  const float* wv_w  = (const float*)d_in[6];
  const float* wv_b  = (const float*)d_in[7];
  const float* wo_w  = (const float*)d_in[8];
  const float* wo_b  = (const float*)d_in[9];
  const float* an_g  = (const float*)d_in[10];
  const float* an_b  = (const float*)d_in[11];
  const float* fc1_w = (const float*)d_in[12];
  const float* fc1_b = (const float*)d_in[13];
  const float* fc2_w = (const float*)d_in[14];
  const float* fc2_b = (const float*)d_in[15];
  const float* fn_g  = (const float*)d_in[16];
  const float* fn_b  = (const float*)d_in[17];
  const float* r1_w  = (const float*)d_in[18];
  const float* r1_b  = (const float*)d_in[19];
  const float* rn_g  = (const float*)d_in[20];
  const float* rn_b  = (const float*)d_in[21];
  const float* r2_w  = (const float*)d_in[22];
  const float* r2_b  = (const float*)d_in[23];
  const float* eA    = (const float*)d_in[24];
  const float* eB    = (const float*)d_in[25];
  float* outf = (float*)d_out;

  const size_t MiB = 1048576;
  const size_t NEED_FULL = 153*MiB;                       // unchunked FFN (m1 = 77.5 MiB)
  const size_t NEED_MIN  = 112*MiB + (size_t)TOK*DIM*2;   // 2-chunk fallback
  if (ws_size < NEED_MIN) return;   // leaves d_out poisoned -> readable failure
  const bool full = (ws_size >= NEED_FULL);
  const int  nc   = full ? 1 : 2;
  const int  MC   = TOK / nc;       // 12608 or 6304
  const size_t offSY = full ? 94*MiB  : 72*MiB;
  const size_t offSZ = full ? 133*MiB : 112*MiB;

  char* ws = (char*)d_ws;
  // weights region (0..16MiB)
  u16*   Wqkv = (u16*)(ws + 0);                    // [2304][768]
  u16*   Wo   = (u16*)(ws + 3538944);              // [768][768]
  u16*   Wfc1 = (u16*)(ws + 4718592);              // [3072][768]
  u16*   Wfc2 = (u16*)(ws + 9437184);              // [768][3072]
  u16*   Wr1  = (u16*)(ws + 14155776);             // [512][768]
  float* qkvb = (float*)(ws + 14942208);           // [2304]
  int*   idxb = (int*)(ws + 14952448);             // [TOK]
  // activation slots
  char* SX = ws + 16*MiB;     // x_b16 -> qkv_b16 -> m1 (full or chunk)
  char* SY = ws + offSY;      // t1 -> x1 (f32)
  char* SZ = ws + offSZ;      // h_b16 -> o_b16 -> h1_b16
  u16*   x_b = (u16*)SX;
  u16*   qkv = (u16*)SX;
  u16*   m1  = (u16*)SX;
  float* t1  = (float*)SY;
  float* x1  = (float*)SY;
  u16*   h_b = (u16*)SZ;
  u16*   ob  = (u16*)SZ;
  u16*   h1  = (u16*)SZ;

  // ---- weight + input conversions ----
  cvt_bf16<<<512, 256, 0, stream>>>(wq_w, Wqkv,               589824);
  cvt_bf16<<<512, 256, 0, stream>>>(wk_w, Wqkv + 589824,      589824);
  cvt_bf16<<<512, 256, 0, stream>>>(wv_w, Wqkv + 2*589824,    589824);
  cvt_bf16<<<512, 256, 0, stream>>>(wo_w, Wo,                 589824);
  cvt_bf16<<<1024, 256, 0, stream>>>(fc1_w, Wfc1,             2359296);
  cvt_bf16<<<1024, 256, 0, stream>>>(fc2_w, Wfc2,             2359296);
  cvt_bf16<<<512, 256, 0, stream>>>(r1_w, Wr1,                393216);
  cvt_bf16<<<2048, 256, 0, stream>>>(x, x_b,                  (long)TOK*DIM);
  concat3<<<3, 256, 0, stream>>>(wq_b, wk_b, wv_b, qkvb);

  // ---- router: t1 = x @ r1_w^T + r1_b (f32), then LN+silu+r2+argmax ----
  gemm_bt<0, false, true, false><<<dim3(4, 99), 256, 0, stream>>>(
      x_b, Wr1, r1_b, nullptr, t1, nullptr, RH_D, TOK, RH_D, DIM);
  router_fin<<<TOK, 64, 0, stream>>>(t1, rn_g, rn_b, r2_w, r2_b, idxb);

  // ---- attention ----
  ln_rows<<<TOK/4, 256, 0, stream>>>(x, an_g, an_b, h_b, TOK);
  gemm_bt<0, false, false, true><<<dim3(18, 99), 256, 0, stream>>>(
      h_b, Wqkv, qkvb, nullptr, nullptr, qkv, 3*DIM, TOK, 3*DIM, DIM);
  attn<<<B_SZ*NHEAD, 256, 0, stream>>>(qkv, ob);
  gemm_bt<0, true, true, false><<<dim3(6, 99), 256, 0, stream>>>(
      ob, Wo, wo_b, x, x1, nullptr, DIM, TOK, DIM, DIM);

  // ---- FFN (full-M if ws allows; else 2 chunks) ----
  ln_rows<<<TOK/4, 256, 0, stream>>>(x1, fn_g, fn_b, h1, TOK);
  for (int c = 0; c < nc; ++c) {
    const int r0 = c * MC;
    const int gy = (MC + 127) / 128;
    gemm_bt<1, false, false, true><<<dim3(24, gy), 256, 0, stream>>>(
        h1 + (long)r0*DIM, Wfc1, fc1_b, nullptr, nullptr, m1, MLP_D, MC, MLP_D, DIM);
    gemm_bt<0, true, true, false><<<dim3(6, gy), 256, 0, stream>>>(
        m1, Wfc2, fc2_b, x1 + (long)r0*DIM, outf + (long)r0*DIM, nullptr, DIM, MC, DIM, MLP_D);
  }

  // ---- routed LoRA experts (identity for key 3) ----
  expert_apply<<<TOK, 256, 0, stream>>>(idxb, eA, eB, outf);
}